// Round 7
// baseline (1322.190 us; speedup 1.0000x reference)
//
#include <hip/hip_runtime.h>

typedef unsigned short u16;
typedef __attribute__((ext_vector_type(8))) short short8;
typedef __attribute__((ext_vector_type(4))) float f32x4;
typedef __attribute__((ext_vector_type(16))) float f32x16;
typedef __attribute__((ext_vector_type(2))) unsigned int u32x2;

#define NPTS 1048576
#define HP 264  // sH row stride in elements (528 B, 16B-aligned)

__device__ __forceinline__ u16 f2b(float f) {
    return (u16)((__float_as_uint(f) + 0x8000u) >> 16);
}
#define INV2PI 0.15915494309189535f
__device__ __forceinline__ float sinrev(float t) {
    t = t - floorf(t);
    return __builtin_amdgcn_sinf(t);
}

// ---------------- weight convert(fp32->bf16) + transpose/pad prepass ----------------
// ws layout (bf16), WT[n][k] row-major in k:
//  WT1  @      0 : 256 x  64   (W1 63x256; k==63 = b1[n] bias fold, act col63=1.0)
//  WT2  @  16384 : 256 x 256
//  WT3  @  81920 : 256 x 256
//  WT4  @ 147456 :  16 x 256
//  WTc1 @ 151552 : 128 x  64   (Wc1 42x128; k==42 = bc1[n]; k>42 -> 0)
//  WTc2 @ 159744 :  16 x 128   (Wc2 128x3, n>=3 -> 0)
__global__ void prep_weights(const float* __restrict__ W1, const float* __restrict__ b1,
                             const float* __restrict__ W2,
                             const float* __restrict__ W3, const float* __restrict__ W4,
                             const float* __restrict__ Wc1, const float* __restrict__ bc1,
                             const float* __restrict__ Wc2,
                             u16* __restrict__ ws) {
    int i = blockIdx.x * 256 + threadIdx.x;
    if (i < 16384) { int n = i >> 6, k = i & 63;  ws[i]          = (k < 63) ? f2b(W1[k * 256 + n]) : f2b(b1[n]); return; }
    i -= 16384;
    if (i < 65536) { int n = i >> 8, k = i & 255; ws[16384 + i]  = f2b(W2[k * 256 + n]); return; }
    i -= 65536;
    if (i < 65536) { int n = i >> 8, k = i & 255; ws[81920 + i]  = f2b(W3[k * 256 + n]); return; }
    i -= 65536;
    if (i < 4096)  { int n = i >> 8, k = i & 255; ws[147456 + i] = f2b(W4[k * 16 + n]); return; }
    i -= 4096;
    if (i < 8192)  { int n = i >> 6, k = i & 63;
                     ws[151552 + i] = (k < 42) ? f2b(Wc1[k * 128 + n]) : ((k == 42) ? f2b(bc1[n]) : (u16)0); return; }
    i -= 8192;
    if (i < 2048)  { int n = i >> 7, k = i & 127; ws[159744 + i] = (n < 3) ? f2b(Wc2[k * 3 + n]) : (u16)0; return; }
}

// ---------------- fused dense layer, 32x32x16, A=weights B=activations ----------------
// Wave: 32 batch rows [row0,+32) x NT*32 neurons [nbase,+NT*32).
// Per kt: 1 LDS act read (reused over NT) + NT weight loads + NT MFMAs.
// Weights flow through an explicit PF-deep rotating register buffer: PF*NT loads
// are in flight at all times -> L2 latency overlapped by MLP, not just TLP.
// D: col(batchrow)=lane&31, row(neuron)=(reg&3)+8*(reg>>2)+4*(lane>>5) -> packed b64 epi.
// All LDS reads precede the internal barrier; writes follow -> in-place safe.
template <int K, int NT, bool RELU, bool BIAS>
__device__ __forceinline__ void dense32(const u16* __restrict__ WT, const float* __restrict__ bias,
                                        u16 (*sH)[HP], int nbase, int row0, int lane) {
    constexpr int NKT = K / 16;
    constexpr int PF = (NKT >= 8) ? 8 : NKT;   // prefetch depth (reg buffer)
    const int ln = lane & 31, kh = lane >> 5;
    const u16* wp[NT];
#pragma unroll
    for (int nt = 0; nt < NT; ++nt)
        wp[nt] = WT + (size_t)(nbase + nt * 32 + ln) * K + kh * 8;
    const u16* actp = &sH[row0 + ln][kh * 8];

    f32x16 acc[NT];
#pragma unroll
    for (int nt = 0; nt < NT; ++nt)
#pragma unroll
        for (int r = 0; r < 16; ++r) acc[nt][r] = 0.f;

    short8 aW[NT][PF];
#pragma unroll
    for (int p = 0; p < PF; ++p)
#pragma unroll
        for (int nt = 0; nt < NT; ++nt)
            aW[nt][p] = *(const short8*)(wp[nt] + p * 16);

#pragma unroll
    for (int kt = 0; kt < NKT; ++kt) {
        const short8 bA = *(const short8*)(actp + kt * 16);
        short8 a[NT];
#pragma unroll
        for (int nt = 0; nt < NT; ++nt) a[nt] = aW[nt][kt % PF];
        if (kt + PF < NKT) {
#pragma unroll
            for (int nt = 0; nt < NT; ++nt)
                aW[nt][kt % PF] = *(const short8*)(wp[nt] + (kt + PF) * 16);
        }
#pragma unroll
        for (int nt = 0; nt < NT; ++nt)
            acc[nt] = __builtin_amdgcn_mfma_f32_32x32x16_bf16(a[nt], bA, acc[nt], 0, 0, 0);
    }
    __syncthreads();
    u16* rowp = &sH[row0 + ln][0];
#pragma unroll
    for (int nt = 0; nt < NT; ++nt)
#pragma unroll
        for (int g = 0; g < 4; ++g) {
            const int mq = nbase + nt * 32 + 8 * g + 4 * kh;   // 4 consecutive neurons
            float v[4];
#pragma unroll
            for (int j = 0; j < 4; ++j) v[j] = acc[nt][4 * g + j];
            if (BIAS) {
                const f32x4 bi = *(const f32x4*)(bias + mq);
#pragma unroll
                for (int j = 0; j < 4; ++j) v[j] += bi[j];
            }
            if (RELU)
#pragma unroll
                for (int j = 0; j < 4; ++j) v[j] = fmaxf(v[j], 0.f);
            unsigned int u[4];
#pragma unroll
            for (int j = 0; j < 4; ++j) u[j] = __float_as_uint(v[j]) + 0x8000u;
            u32x2 d;
            d.x = __builtin_amdgcn_perm(u[1], u[0], 0x07060302);
            d.y = __builtin_amdgcn_perm(u[3], u[2], 0x07060302);
            *(u32x2*)(rowp + mq) = d;   // ds_write_b64
        }
}

__global__ __launch_bounds__(512, 4) void ngp_fused(
    const float* __restrict__ pos, const float* __restrict__ dir, const u16* __restrict__ ws,
    const float* __restrict__ b2, const float* __restrict__ b3,
    const float* __restrict__ b4, const float* __restrict__ bc2,
    float* __restrict__ out) {
    __shared__ __align__(16) u16 sH[64][HP];
    __shared__ __align__(16) u16 sDir[64][28];
    const int t = threadIdx.x;
    const int lane = t & 63;
    const int w = t >> 6;           // 8 waves
    const int lr = lane & 15, q = lane >> 4;
    const int wm = w & 1;           // 32-row half
    const int wn = w >> 1;          // neuron quarter
    const long rb = (long)blockIdx.x * 64;

    const u16* WT1  = ws;
    const u16* WT2  = ws + 16384;
    const u16* WT3  = ws + 81920;
    const u16* WT4  = ws + 147456;
    const u16* WTc1 = ws + 151552;
    const u16* WTc2 = ws + 159744;

    // ---- encodings: threads 0-255 pos-enc -> sH[r][0..63]; 256-511 dir-enc -> sDir ----
    if (t < 256) {
        const int r = t & 63;
        const int g = t >> 6;       // 0..3
        const long row = rb + r;
        float xn[3];
#pragma unroll
        for (int c = 0; c < 3; ++c) xn[c] = pos[row * 3 + c] * (1.0f / 1.5f);
        if (g == 3) {
            sH[r][0] = f2b(xn[0]); sH[r][1] = f2b(xn[1]); sH[r][2] = f2b(xn[2]);
            sH[r][63] = 0x3F80;     // 1.0 — multiplies WT1[n][63] = b1[n]
#pragma unroll
            for (int c = 0; c < 3; ++c) {
                float tv = xn[c] * 512.f * INV2PI;  // degree 9
                sH[r][3 + 27 + c]  = f2b(sinrev(tv));
                sH[r][33 + 27 + c] = f2b(sinrev(tv + 0.25f));
            }
        } else {
#pragma unroll
            for (int dd = 0; dd < 3; ++dd) {
                const int d = g * 3 + dd;
                const float sc = (float)(1 << d);
#pragma unroll
                for (int c = 0; c < 3; ++c) {
                    float tv = xn[c] * sc * INV2PI;
                    sH[r][3 + d * 3 + c]  = f2b(sinrev(tv));
                    sH[r][33 + d * 3 + c] = f2b(sinrev(tv + 0.25f));
                }
            }
        }
    } else {
        const int t2 = t - 256;
        const int r = t2 & 63;
        const int g = t2 >> 6;      // 0..3
        const long row = rb + r;
        const float dx = dir[row * 3 + 0];
        const float dy = dir[row * 3 + 1];
        const float dz = dir[row * 3 + 2];
        const float nrm = sqrtf(dx * dx + dy * dy + dz * dz);
        const float inv = 1.f / fmaxf(nrm, 1e-12f);
        const float dn[3] = {dx * inv, dy * inv, dz * inv};
        if (g == 0) { sDir[r][0] = f2b(dn[0]); sDir[r][1] = f2b(dn[1]); sDir[r][2] = f2b(dn[2]); }
        const float sc = (float)(1 << g);  // degree = g (0..3)
#pragma unroll
        for (int c = 0; c < 3; ++c) {
            float tv = dn[c] * sc * INV2PI;
            sDir[r][3 + g * 3 + c]  = f2b(sinrev(tv));
            sDir[r][15 + g * 3 + c] = f2b(sinrev(tv + 0.25f));
        }
    }
    __syncthreads();
    dense32<64, 2, true, false>(WT1, nullptr, sH, wn * 64, wm * 32, lane);
    __syncthreads();
    dense32<256, 2, true, true>(WT2, b2, sH, wn * 64, wm * 32, lane);
    __syncthreads();
    dense32<256, 2, true, true>(WT3, b3, sH, wn * 64, wm * 32, lane);
    __syncthreads();

    // ---- layer 4 (256 -> 16): waves 0-3, 16 rows each (16x16x32, neuron = lr) ----
    f32x4 acc4 = {0.f, 0.f, 0.f, 0.f};
    if (w < 4) {
#pragma unroll
        for (int kt = 0; kt < 8; ++kt) {
            const short8 aF = *(const short8*)&sH[w * 16 + lr][kt * 32 + q * 8];
            const short8 bF = *(const short8*)(WT4 + lr * 256 + kt * 32 + q * 8);
            acc4 = __builtin_amdgcn_mfma_f32_16x16x32_bf16(aF, bF, acc4, 0, 0, 0);
        }
    }
    __syncthreads();
    if (w < 4) {
        const float bi = b4[lr];
#pragma unroll
        for (int r = 0; r < 4; ++r) {
            const float v = acc4[r] + bi;
            const int gm = w * 16 + q * 4 + r;
            if (lr == 0)
                out[3 * (long)NPTS + rb + gm] = __expf(v - 1.f);
            else
                sH[gm][lr - 1] = f2b(v);   // feat -> cols 0..14
        }
    } else {
        // splice dir encoding: sH[r][15..41] = sDir[r][0..26]; col42 = 1.0 (bias); 43..63 = 0
        const int t2 = t - 256;
        const int r = t2 & 63;
        const int g = t2 >> 6;      // 0..3
        for (int j = g; j < 27; j += 4) sH[r][15 + j] = sDir[r][j];
        if (g == 0) sH[r][42] = 0x3F80;  // 1.0 — multiplies WTc1[n][42] = bc1[n]
        for (int j = 43 + g; j < 64; j += 4) sH[r][j] = 0;
    }
    __syncthreads();
    dense32<64, 1, true, false>(WTc1, nullptr, sH, wn * 32, wm * 32, lane);
    __syncthreads();

    // ---- color head (128 -> 3): waves 0-3, 16 rows each (16x16x32), sigmoid -> rgb ----
    if (w < 4) {
        f32x4 acc = {0.f, 0.f, 0.f, 0.f};
#pragma unroll
        for (int kt = 0; kt < 4; ++kt) {
            const short8 aF = *(const short8*)&sH[w * 16 + lr][kt * 32 + q * 8];
            const short8 bF = *(const short8*)(WTc2 + lr * 128 + kt * 32 + q * 8);
            acc = __builtin_amdgcn_mfma_f32_16x16x32_bf16(aF, bF, acc, 0, 0, 0);
        }
        if (lr < 3) {
            const float bi = bc2[lr];
#pragma unroll
            for (int r = 0; r < 4; ++r) {
                const float v = acc[r] + bi;
                const float sg = 1.f / (1.f + __expf(-v));
                const int gm = w * 16 + q * 4 + r;
                out[(rb + gm) * 3 + lr] = sg;
            }
        }
    }
}

extern "C" void kernel_launch(void* const* d_in, const int* in_sizes, int n_in,
                              void* d_out, int out_size, void* d_ws, size_t ws_size,
                              hipStream_t stream) {
    const float* pos = (const float*)d_in[0];
    const float* dir = (const float*)d_in[1];
    const float* W1  = (const float*)d_in[2];
    const float* b1  = (const float*)d_in[3];
    const float* W2  = (const float*)d_in[4];
    const float* b2  = (const float*)d_in[5];
    const float* W3  = (const float*)d_in[6];
    const float* b3  = (const float*)d_in[7];
    const float* W4  = (const float*)d_in[8];
    const float* b4  = (const float*)d_in[9];
    const float* Wc1 = (const float*)d_in[10];
    const float* bc1 = (const float*)d_in[11];
    const float* Wc2 = (const float*)d_in[12];
    const float* bc2 = (const float*)d_in[13];
    u16* ws   = (u16*)d_ws;
    float* out = (float*)d_out;

    prep_weights<<<633, 256, 0, stream>>>(W1, b1, W2, W3, W4, Wc1, bc1, Wc2, ws);
    ngp_fused<<<NPTS / 64, 512, 0, stream>>>(pos, dir, ws, b2, b3, b4, bc2, out);
}

// Round 8
// 693.412 us; speedup vs baseline: 1.9068x; 1.9068x over previous
//
#include <hip/hip_runtime.h>

typedef unsigned short u16;
typedef __attribute__((ext_vector_type(8))) short short8;
typedef __attribute__((ext_vector_type(4))) float f32x4;
typedef __attribute__((ext_vector_type(16))) float f32x16;
typedef __attribute__((ext_vector_type(2))) unsigned int u32x2;

#define NPTS 1048576
#define HP 264     // LDS row stride in elements (528 B, 16B-aligned)
#define TILES 32   // batch tiles (32 rows each) per block
#define NBLK (NPTS / (32 * TILES))   // 1024 blocks

__device__ __forceinline__ u16 f2b(float f) {
    return (u16)((__float_as_uint(f) + 0x8000u) >> 16);
}
#define INV2PI 0.15915494309189535f
__device__ __forceinline__ float sinrev(float t) {
    t = t - floorf(t);
    return __builtin_amdgcn_sinf(t);
}

// ---------------- weight convert(fp32->bf16) + transpose/pad prepass ----------------
// ws layout (bf16), WT[n][k] row-major in k:
//  WT1  @      0 : 256 x  64   (W1 63x256; k==63 = b1[n] bias fold, act col63=1.0)
//  WT2  @  16384 : 256 x 256
//  WT3  @  81920 : 256 x 256
//  WT4  @ 147456 :  16 x 256
//  WTc1 @ 151552 : 128 x  64   (Wc1 42x128; k==42 = bc1[n]; k>42 -> 0)
//  WTc2 @ 159744 :  16 x 128   (Wc2 128x3, n>=3 -> 0)
__global__ void prep_weights(const float* __restrict__ W1, const float* __restrict__ b1,
                             const float* __restrict__ W2,
                             const float* __restrict__ W3, const float* __restrict__ W4,
                             const float* __restrict__ Wc1, const float* __restrict__ bc1,
                             const float* __restrict__ Wc2,
                             u16* __restrict__ ws) {
    int i = blockIdx.x * 256 + threadIdx.x;
    if (i < 16384) { int n = i >> 6, k = i & 63;  ws[i]          = (k < 63) ? f2b(W1[k * 256 + n]) : f2b(b1[n]); return; }
    i -= 16384;
    if (i < 65536) { int n = i >> 8, k = i & 255; ws[16384 + i]  = f2b(W2[k * 256 + n]); return; }
    i -= 65536;
    if (i < 65536) { int n = i >> 8, k = i & 255; ws[81920 + i]  = f2b(W3[k * 256 + n]); return; }
    i -= 65536;
    if (i < 4096)  { int n = i >> 8, k = i & 255; ws[147456 + i] = f2b(W4[k * 16 + n]); return; }
    i -= 4096;
    if (i < 8192)  { int n = i >> 6, k = i & 63;
                     ws[151552 + i] = (k < 42) ? f2b(Wc1[k * 128 + n]) : ((k == 42) ? f2b(bc1[n]) : (u16)0); return; }
    i -= 8192;
    if (i < 2048)  { int n = i >> 7, k = i & 127; ws[159744 + i] = (n < 3) ? f2b(Wc2[k * 3 + n]) : (u16)0; return; }
}

// Epilogue for 32x32x16 (A=weights, B=acts): lane = batch row, regs = 16 neurons.
// reg r -> neuron (r&3)+8*(r>>2)+4*kh within [nbase,+32): packed b64 writes (R5-proven).
template <bool BIAS, bool RELU>
__device__ __forceinline__ void epi32(const f32x16& acc, u16* rowp, const float* bias,
                                      int nbase, int kh) {
#pragma unroll
    for (int g = 0; g < 4; ++g) {
        const int mq = nbase + 8 * g + 4 * kh;
        float v[4];
#pragma unroll
        for (int j = 0; j < 4; ++j) v[j] = acc[4 * g + j];
        if (BIAS) {
            const f32x4 bi = *(const f32x4*)(bias + mq);
#pragma unroll
            for (int j = 0; j < 4; ++j) v[j] += bi[j];
        }
        if (RELU)
#pragma unroll
            for (int j = 0; j < 4; ++j) v[j] = fmaxf(v[j], 0.f);
        unsigned int u[4];
#pragma unroll
        for (int j = 0; j < 4; ++j) u[j] = __float_as_uint(v[j]) + 0x8000u;
        u32x2 d;
        d.x = __builtin_amdgcn_perm(u[1], u[0], 0x07060302);
        d.y = __builtin_amdgcn_perm(u[3], u[2], 0x07060302);
        *(u32x2*)(rowp + mq) = d;
    }
}

// Persistent-weight fused MLP. 1024 blocks x 512 threads; each block loads its
// waves' W1/W2/W3/Wc1 fragment slices into registers ONCE, then processes 32
// batch-tiles of 32 rows with ping-pong LDS buffers (7 barriers/tile, K-loops
// contain zero global loads for the big layers).
__global__ __launch_bounds__(512, 2) void ngp_fused(
    const float* __restrict__ pos, const float* __restrict__ dir, const u16* __restrict__ ws,
    const float* __restrict__ b2, const float* __restrict__ b3,
    const float* __restrict__ b4, const float* __restrict__ bc2,
    float* __restrict__ out) {
    __shared__ __align__(16) u16 sB[2][32][HP];
    __shared__ __align__(16) u16 sDir[32][28];
    const int t = threadIdx.x;
    const int lane = t & 63;
    const int w = t >> 6;            // 8 waves
    const int ln = lane & 31, kh = lane >> 5;   // 32x32 frag coords
    const int lr = lane & 15, q = lane >> 4;    // 16x16 frag coords

    const u16* WT1  = ws;
    const u16* WT2  = ws + 16384;
    const u16* WT3  = ws + 81920;
    const u16* WT4  = ws + 147456;
    const u16* WTc1 = ws + 151552;
    const u16* WTc2 = ws + 159744;

    // ---- resident weight fragments (loaded once per block) ----
    short8 w1r[4], w2r[16], w3r[16], wc1r[4];
    {
        const u16* p = WT1 + (size_t)(w * 32 + ln) * 64 + kh * 8;
#pragma unroll
        for (int kt = 0; kt < 4; ++kt) w1r[kt] = *(const short8*)(p + kt * 16);
    }
    {
        const u16* p = WT2 + (size_t)(w * 32 + ln) * 256 + kh * 8;
#pragma unroll
        for (int kt = 0; kt < 16; ++kt) w2r[kt] = *(const short8*)(p + kt * 16);
    }
    {
        const u16* p = WT3 + (size_t)(w * 32 + ln) * 256 + kh * 8;
#pragma unroll
        for (int kt = 0; kt < 16; ++kt) w3r[kt] = *(const short8*)(p + kt * 16);
    }
    if (w < 4) {
        const u16* p = WTc1 + (size_t)(w * 32 + ln) * 64 + kh * 8;
#pragma unroll
        for (int kt = 0; kt < 4; ++kt) wc1r[kt] = *(const short8*)(p + kt * 16);
    }

    for (int it = 0; it < TILES; ++it) {
        const long rb = ((long)blockIdx.x * TILES + it) * 32;

        // ---- encodings: waves 0-3 pos -> sB[0][r][0..63]; waves 4-7 dir -> sDir ----
        if (t < 256) {
            const int r = t >> 3, g = t & 7;     // 8 threads per row
            const long row = rb + r;
            float xn[3];
#pragma unroll
            for (int c = 0; c < 3; ++c) xn[c] = pos[row * 3 + c] * (1.0f / 1.5f);
            if (g < 5) {
#pragma unroll
                for (int dd = 0; dd < 2; ++dd) {
                    const int d = 2 * g + dd;
                    const float sc = (float)(1 << d);
#pragma unroll
                    for (int c = 0; c < 3; ++c) {
                        float tv = xn[c] * sc * INV2PI;
                        sB[0][r][3 + d * 3 + c]  = f2b(sinrev(tv));
                        sB[0][r][33 + d * 3 + c] = f2b(sinrev(tv + 0.25f));
                    }
                }
            } else if (g == 5) {
                sB[0][r][0] = f2b(xn[0]); sB[0][r][1] = f2b(xn[1]); sB[0][r][2] = f2b(xn[2]);
                sB[0][r][63] = 0x3F80;   // 1.0 -> b1 fold
            }
        } else {
            const int t2 = t - 256;
            const int r = t2 >> 3, g = t2 & 7;
            const long row = rb + r;
            const float dx = dir[row * 3 + 0];
            const float dy = dir[row * 3 + 1];
            const float dz = dir[row * 3 + 2];
            const float nrm = sqrtf(dx * dx + dy * dy + dz * dz);
            const float inv = 1.f / fmaxf(nrm, 1e-12f);
            const float dn[3] = {dx * inv, dy * inv, dz * inv};
            if (g < 4) {
                const float sc = (float)(1 << g);
#pragma unroll
                for (int c = 0; c < 3; ++c) {
                    float tv = dn[c] * sc * INV2PI;
                    sDir[r][3 + g * 3 + c]  = f2b(sinrev(tv));
                    sDir[r][15 + g * 3 + c] = f2b(sinrev(tv + 0.25f));
                }
            } else if (g == 4) {
                sDir[r][0] = f2b(dn[0]); sDir[r][1] = f2b(dn[1]); sDir[r][2] = f2b(dn[2]);
            }
        }
        __syncthreads();

        // ---- L1 (64 -> 256): sB0 -> sB1, resident w1r ----
        {
            f32x16 acc;
#pragma unroll
            for (int r = 0; r < 16; ++r) acc[r] = 0.f;
#pragma unroll
            for (int kt = 0; kt < 4; ++kt) {
                const short8 bA = *(const short8*)&sB[0][ln][kt * 16 + kh * 8];
                acc = __builtin_amdgcn_mfma_f32_32x32x16_bf16(w1r[kt], bA, acc, 0, 0, 0);
            }
            epi32<false, true>(acc, &sB[1][ln][0], nullptr, w * 32, kh);
        }
        __syncthreads();

        // ---- L2 (256 -> 256): sB1 -> sB0, resident w2r ----
        {
            f32x16 acc;
#pragma unroll
            for (int r = 0; r < 16; ++r) acc[r] = 0.f;
#pragma unroll
            for (int kt = 0; kt < 16; ++kt) {
                const short8 bA = *(const short8*)&sB[1][ln][kt * 16 + kh * 8];
                acc = __builtin_amdgcn_mfma_f32_32x32x16_bf16(w2r[kt], bA, acc, 0, 0, 0);
            }
            epi32<true, true>(acc, &sB[0][ln][0], b2, w * 32, kh);
        }
        __syncthreads();

        // ---- L3 (256 -> 256): sB0 -> sB1, resident w3r ----
        {
            f32x16 acc;
#pragma unroll
            for (int r = 0; r < 16; ++r) acc[r] = 0.f;
#pragma unroll
            for (int kt = 0; kt < 16; ++kt) {
                const short8 bA = *(const short8*)&sB[0][ln][kt * 16 + kh * 8];
                acc = __builtin_amdgcn_mfma_f32_32x32x16_bf16(w3r[kt], bA, acc, 0, 0, 0);
            }
            epi32<true, true>(acc, &sB[1][ln][0], b3, w * 32, kh);
        }
        __syncthreads();

        // ---- L4 (256 -> 16) on waves 2,3 ; dir-splice on waves 0,1,4..7 ----
        if (w == 2 || w == 3) {
            const int rbase = (w - 2) * 16;
            f32x4 acc = {0.f, 0.f, 0.f, 0.f};
#pragma unroll
            for (int kt = 0; kt < 8; ++kt) {
                const short8 aF = *(const short8*)&sB[1][rbase + lr][kt * 32 + q * 8];
                const short8 bF = *(const short8*)(WT4 + lr * 256 + kt * 32 + q * 8);
                acc = __builtin_amdgcn_mfma_f32_16x16x32_bf16(aF, bF, acc, 0, 0, 0);
            }
            const float bi = b4[lr];
#pragma unroll
            for (int r = 0; r < 4; ++r) {
                const float v = acc[r] + bi;
                const int gm = rbase + q * 4 + r;
                if (lr == 0)
                    out[3 * (long)NPTS + rb + gm] = __expf(v - 1.f);
                else
                    sB[0][gm][lr - 1] = f2b(v);   // feat -> cols 0..14
            }
        } else {
            const int ws6 = (w < 2) ? w : (w - 2);   // 0..5
            const int L = ws6 * 64 + lane;           // 0..383
            const int r = L & 31;
            const int j = L >> 5;                    // 0..11 -> cols 15+4j..18+4j
#pragma unroll
            for (int cc = 0; cc < 4; ++cc) {
                const int c = 15 + 4 * j + cc;
                sB[0][r][c] = (c < 42) ? sDir[r][c - 15] : ((c == 42) ? (u16)0x3F80 : (u16)0);
            }
            if (j == 11) sB[0][r][63] = 0;
        }
        __syncthreads();

        // ---- ch1 (42 -> 128): sB0 -> sB1, waves 0-3, resident wc1r ----
        if (w < 4) {
            f32x16 acc;
#pragma unroll
            for (int r = 0; r < 16; ++r) acc[r] = 0.f;
#pragma unroll
            for (int kt = 0; kt < 4; ++kt) {
                const short8 bA = *(const short8*)&sB[0][ln][kt * 16 + kh * 8];
                acc = __builtin_amdgcn_mfma_f32_32x32x16_bf16(wc1r[kt], bA, acc, 0, 0, 0);
            }
            epi32<false, true>(acc, &sB[1][ln][0], nullptr, w * 32, kh);
        }
        __syncthreads();

        // ---- head (128 -> 3): waves 4,5, sigmoid -> rgb ----
        if (w == 4 || w == 5) {
            const int rbase = (w - 4) * 16;
            f32x4 acc = {0.f, 0.f, 0.f, 0.f};
#pragma unroll
            for (int kt = 0; kt < 4; ++kt) {
                const short8 aF = *(const short8*)&sB[1][rbase + lr][kt * 32 + q * 8];
                const short8 bF = *(const short8*)(WTc2 + lr * 128 + kt * 32 + q * 8);
                acc = __builtin_amdgcn_mfma_f32_16x16x32_bf16(aF, bF, acc, 0, 0, 0);
            }
            if (lr < 3) {
                const float bi = bc2[lr];
#pragma unroll
                for (int r = 0; r < 4; ++r) {
                    const float v = acc[r] + bi;
                    const float sg = 1.f / (1.f + __expf(-v));
                    out[(rb + rbase + q * 4 + r) * 3 + lr] = sg;
                }
            }
        }
        __syncthreads();
    }
}

extern "C" void kernel_launch(void* const* d_in, const int* in_sizes, int n_in,
                              void* d_out, int out_size, void* d_ws, size_t ws_size,
                              hipStream_t stream) {
    const float* pos = (const float*)d_in[0];
    const float* dir = (const float*)d_in[1];
    const float* W1  = (const float*)d_in[2];
    const float* b1  = (const float*)d_in[3];
    const float* W2  = (const float*)d_in[4];
    const float* b2  = (const float*)d_in[5];
    const float* W3  = (const float*)d_in[6];
    const float* b3  = (const float*)d_in[7];
    const float* W4  = (const float*)d_in[8];
    const float* b4  = (const float*)d_in[9];
    const float* Wc1 = (const float*)d_in[10];
    const float* bc1 = (const float*)d_in[11];
    const float* Wc2 = (const float*)d_in[12];
    const float* bc2 = (const float*)d_in[13];
    u16* ws   = (u16*)d_ws;
    float* out = (float*)d_out;

    prep_weights<<<633, 256, 0, stream>>>(W1, b1, W2, W3, W4, Wc1, bc1, Wc2, ws);
    ngp_fused<<<NBLK, 512, 0, stream>>>(pos, dir, ws, b2, b3, b4, bc2, out);
}